// Round 5
// baseline (976.434 us; speedup 1.0000x reference)
//
#include <hip/hip_runtime.h>
#include <hip/hip_bf16.h>

// JetBlock forward: B=2, T=2048, HID=2048, H=16, DK=DV=128, W=4
//
// Round 9: 4-segment superposition recurrence (7 roles: 4 real + 3 basis,
// 448 blocks, depth 16 chunks) with LDS diet to 2 blocks/CU (~67 KB):
// KT16 single-buffered + psA-prescaled (Utp16 dropped), V/W0L fp16 with
// row-keyed block swizzle, O0L eliminated (Q*S0 frags stay in registers --
// MFMA C-layout == phase-C write map), At32 padded 32->36. State chain
// composed by a tiny MFMA kernel: SinS_{i+1} = SinS_i @ Mst_i + Sloc_i
// (stored-transpose layout makes this a plain matmul); 3-seg apply_basis.

typedef _Float16 v8h __attribute__((ext_vector_type(8)));
typedef _Float16 v4h __attribute__((ext_vector_type(4)));
typedef _Float16 v2h __attribute__((ext_vector_type(2)));
typedef float    v4f __attribute__((ext_vector_type(4)));

__device__ __forceinline__ void gload16(const void* g, void* l) {
  __builtin_amdgcn_global_load_lds(
      (const __attribute__((address_space(1))) unsigned int*)g,
      (__attribute__((address_space(3))) unsigned int*)l, 16, 0, 0);
}

// row-keyed block swizzle for [32][64] f16 tiles (spreads rg*8-row reads)
__device__ __forceinline__ int sw64(int r, int c) {
  return (c & 7) | ((((c >> 3) ^ (r & 7) ^ (r >> 3)) & 7) << 3);
}

// ---------------------------------------------------------------- transpose
// src [R][C] fp32 -> dst [C][R] fp16
__global__ __launch_bounds__(256)
void transpose_cast(const float* __restrict__ src, _Float16* __restrict__ dst,
                    int R, int C)
{
  __shared__ float tile[32][33];
  int c0 = blockIdx.x * 32, r0 = blockIdx.y * 32;
  int tx = threadIdx.x & 31, ty = threadIdx.x >> 5;  // ty 0..7
  #pragma unroll
  for (int i = 0; i < 32; i += 8)
    tile[ty + i][tx] = src[(size_t)(r0 + ty + i) * C + c0 + tx];
  __syncthreads();
  #pragma unroll
  for (int i = 0; i < 32; i += 8)
    dst[(size_t)(c0 + ty + i) * R + r0 + tx] = (_Float16)tile[tx][ty + i];
}

// ---------------------------------------------------------------- cast
__global__ __launch_bounds__(256)
void cast_f32_f16(const float* __restrict__ src, _Float16* __restrict__ dst, int n4)
{
  int i = blockIdx.x * 256 + threadIdx.x;
  if (i >= n4) return;
  float4 v = ((const float4*)src)[i];
  v4h h = {(_Float16)v.x, (_Float16)v.y, (_Float16)v.z, (_Float16)v.w};
  *(v4h*)&dst[4 * (size_t)i] = h;
}

// ---------------------------------------------------------------- GEMM 256x256 8-phase
// C[M][N] = A[M][K] * Bt[N][K]^T, fp16 in, fp32 accumulate.
// MODE 0: fp32 store. 1: silu -> f16. 2: +bias -> f16. 3: plain f16.
// (structure unchanged from Round 5 -- see that round's derivation)
template<int MODE>
__global__ __launch_bounds__(512, 2)
void gemm256(const _Float16* __restrict__ A, const _Float16* __restrict__ Bt,
             void* __restrict__ Cout, const float* __restrict__ bias,
             int M, int N, int K)
{
  __shared__ _Float16 lds[65536];   // 128 KiB
  const int tid  = threadIdx.x;
  const int lane = tid & 63;
  const int wid  = tid >> 6;
  const int wm   = wid >> 2;        // 0..1
  const int wn   = wid & 3;         // 0..3
  const int l16  = lane & 15;
  const int q8   = (lane >> 4) * 8;
  const int swzx = (l16 & 7) << 3;  // row&7 == l16&7 for all frag rows

  // XCD-aware bijective swizzle (gridDim.x % 8 == 0 at all call sites)
  const int nbx = N >> 8;
  const int cpx = gridDim.x >> 3;
  const int swz = (blockIdx.x & 7) * cpx + (blockIdx.x >> 3);
  const int bm0 = (swz / nbx) << 8;
  const int bn0 = (swz % nbx) << 8;

  const _Float16* Abase = A  + (size_t)bm0 * K;
  const _Float16* Bbase = Bt + (size_t)bn0 * K;

  const int r0 = tid >> 3;                              // 0..63
  const int cs = ((tid & 7) * 8) ^ ((r0 & 7) << 3);     // f16 units

#define SLOTA(par, half) (lds + ((par) * 2 + (half)) * 8192)
#define SLOTB(par, half) (lds + 32768 + ((par) * 2 + (half)) * 8192)
#define STAGE(basep, kt, slot) do {                                        \
    _Float16* sst_ = (slot);                                               \
    gload16((basep) + (size_t)r0 * K + (kt) + cs, sst_ + tid * 8);         \
    gload16((basep) + (size_t)(r0 + 64) * K + (kt) + cs,                   \
            sst_ + 4096 + tid * 8);                                        \
  } while (0)
#define LOADA(par, mh) do {                                                \
    const _Float16* sld_ = SLOTA(par, mh);                                 \
    _Pragma("unroll")                                                      \
    for (int ks = 0; ks < 2; ks++)                                         \
      _Pragma("unroll")                                                    \
      for (int mi = 0; mi < 4; mi++)                                       \
        af[ks][mi] = *(const v8h*)&sld_[(wm * 64 + mi * 16 + l16) * 64 +   \
                                        ((ks * 32 + q8) ^ swzx)];          \
  } while (0)
#define LOADB(par, nh) do {                                                \
    const _Float16* sld_ = SLOTB(par, nh);                                 \
    _Pragma("unroll")                                                      \
    for (int ks = 0; ks < 2; ks++)                                         \
      _Pragma("unroll")                                                    \
      for (int ni = 0; ni < 2; ni++)                                       \
        bf[ks][ni] = *(const v8h*)&sld_[(wn * 32 + ni * 16 + l16) * 64 +   \
                                        ((ks * 32 + q8) ^ swzx)];          \
  } while (0)
#define MMAC(mh, nh) do {                                                  \
    __builtin_amdgcn_s_setprio(1);                                         \
    _Pragma("unroll")                                                      \
    for (int ks = 0; ks < 2; ks++)                                         \
      _Pragma("unroll")                                                    \
      for (int mi = 0; mi < 4; mi++)                                       \
        _Pragma("unroll")                                                  \
        for (int ni = 0; ni < 2; ni++)                                     \
          acc[mh][mi][nh][ni] = __builtin_amdgcn_mfma_f32_16x16x32_f16(    \
              af[ks][mi], bf[ks][ni], acc[mh][mi][nh][ni], 0, 0, 0);       \
    __builtin_amdgcn_s_setprio(0);                                         \
  } while (0)

  v4f acc[2][4][2][2];
  #pragma unroll
  for (int mh = 0; mh < 2; mh++)
    #pragma unroll
    for (int mi = 0; mi < 4; mi++)
      #pragma unroll
      for (int nh = 0; nh < 2; nh++)
        #pragma unroll
        for (int ni = 0; ni < 2; ni++)
          acc[mh][mi][nh][ni] = v4f{0.f, 0.f, 0.f, 0.f};
  v8h af[2][4], bf[2][2];

  const int nt = K >> 6;   // >= 32 at all call sites

  // prologue: tile0 fully + t1.Aa + t1.Bb (steady-state pattern primed)
  STAGE(Abase,                   0,  SLOTA(0, 0));
  STAGE(Bbase,                   0,  SLOTB(0, 0));
  STAGE(Abase + (size_t)128 * K, 0,  SLOTA(0, 1));
  STAGE(Bbase + (size_t)128 * K, 0,  SLOTB(0, 1));
  STAGE(Abase,                   64, SLOTA(1, 0));
  STAGE(Bbase + (size_t)128 * K, 64, SLOTB(1, 1));
  asm volatile("s_waitcnt vmcnt(4)" ::: "memory");
  __builtin_amdgcn_s_barrier();

  for (int T = 0; T < nt; T++) {
    const int par = T & 1;
    const int kt1 = (T + 1) << 6;
    const int kt2 = (T + 2) << 6;
    // ph1 (0,0)
    LOADA(par, 0);
    LOADB(par, 0);
    if (T + 1 < nt) STAGE(Abase + (size_t)128 * K, kt1, SLOTA(par ^ 1, 1));
    __builtin_amdgcn_s_barrier();
    MMAC(0, 0);
    __builtin_amdgcn_s_barrier();
    // ph2 (0,1)
    LOADB(par, 1);
    if (T + 1 < nt) STAGE(Bbase, kt1, SLOTB(par ^ 1, 0));
    __builtin_amdgcn_s_barrier();
    MMAC(0, 1);
    __builtin_amdgcn_s_barrier();
    // ph3 (1,1)
    LOADA(par, 1);
    if (T + 2 < nt) STAGE(Abase, kt2, SLOTA(par, 0));
    __builtin_amdgcn_s_barrier();
    MMAC(1, 1);
    __builtin_amdgcn_s_barrier();
    // ph4 (1,0)
    LOADB(par, 0);
    if (T + 2 < nt) STAGE(Bbase + (size_t)128 * K, kt2, SLOTB(par, 1));
    __builtin_amdgcn_s_barrier();
    MMAC(1, 0);
    if (T + 2 < nt) { asm volatile("s_waitcnt vmcnt(4)" ::: "memory"); }
    else            { asm volatile("s_waitcnt vmcnt(0)" ::: "memory"); }
    __builtin_amdgcn_s_barrier();
  }

  const int q4 = (lane >> 4) * 4;
  #pragma unroll
  for (int mh = 0; mh < 2; mh++) {
    #pragma unroll
    for (int mi = 0; mi < 4; mi++) {
      #pragma unroll
      for (int nh = 0; nh < 2; nh++) {
        #pragma unroll
        for (int ni = 0; ni < 2; ni++) {
          const int gn = bn0 + nh * 128 + wn * 32 + ni * 16 + l16;
          #pragma unroll
          for (int r = 0; r < 4; r++) {
            const int gm = bm0 + mh * 128 + wm * 64 + mi * 16 + q4 + r;
            float val = acc[mh][mi][nh][ni][r];
            size_t offc = (size_t)gm * N + gn;
            if (MODE == 0) {
              ((float*)Cout)[offc] = val;
            } else if (MODE == 1) {
              float s = val / (1.0f + expf(-val));
              ((_Float16*)Cout)[offc] = (_Float16)s;
            } else if (MODE == 2) {
              float s = val + bias[gn];
              ((_Float16*)Cout)[offc] = (_Float16)s;
            } else {
              ((_Float16*)Cout)[offc] = (_Float16)val;
            }
          }
        }
      }
    }
  }
#undef SLOTA
#undef SLOTB
#undef STAGE
#undef LOADA
#undef LOADB
#undef MMAC
}

// ---------------------------------------------------------------- conv + silu (per 2048-row chunk == one batch)
__global__ __launch_bounds__(256)
void conv_silu(const _Float16* __restrict__ vg, const _Float16* __restrict__ kernc,
               float* __restrict__ vprime, int chunk)
{
  int idx = blockIdx.x * 256 + threadIdx.x;   // 2048*2048
  int btl = idx >> 11;                        // 0..2047 == t (chunk aligned to batch)
  int d   = idx & 2047;
  int btg = chunk * 2048 + btl;
  v4h kv = *(const v4h*)&kernc[(size_t)btl * 8192 + d * 4];
  float kw0 = (float)kv[0], kw1 = (float)kv[1], kw2 = (float)kv[2], kw3 = (float)kv[3];
  const _Float16* vcol = vg + d;
  float acc = kw3 * (float)vcol[(size_t)btg * 4096];
  if (btl >= 1) acc += kw2 * (float)vcol[(size_t)(btg - 1) * 4096];
  if (btl >= 2) acc += kw1 * (float)vcol[(size_t)(btg - 2) * 4096];
  if (btl >= 3) acc += kw0 * (float)vcol[(size_t)(btg - 3) * 4096];
  vprime[(size_t)btg * 2048 + d] = acc / (1.0f + expf(-acc));
}

// ---------------------------------------------------------------- beta / glog (fp32 x)
__global__ __launch_bounds__(256)
void beta_decay(const float* __restrict__ x, const float* __restrict__ Wb,
                const float* __restrict__ Wa, const float* __restrict__ dt_bias,
                const float* __restrict__ A_log,
                float* __restrict__ beta, float* __restrict__ glog)
{
  __shared__ float xs[2048];
  __shared__ float red[8][32];
  int row = blockIdx.x;
  int tid = threadIdx.x;
  for (int i = tid; i < 2048; i += 256) xs[i] = x[(size_t)row * 2048 + i];
  __syncthreads();
  int j = tid & 31, kg = tid >> 5;
  const float* W = (j < 16) ? Wb : Wa;
  int jj = j & 15;
  float acc = 0.f;
  int k0 = kg * 256;
  for (int k = k0; k < k0 + 256; k++) acc += xs[k] * W[(size_t)k * 16 + jj];
  red[kg][j] = acc;
  __syncthreads();
  if (tid < 32) {
    float s = 0.f;
    #pragma unroll
    for (int g2 = 0; g2 < 8; g2++) s += red[g2][tid];
    int hh = tid & 15;
    if (tid < 16) {
      beta[(size_t)row * 16 + hh] = 1.0f / (1.0f + expf(-s));
    } else {
      float tt = s + dt_bias[hh];
      float sp = (tt > 20.f) ? tt : log1pf(expf(tt));
      glog[(size_t)row * 16 + hh] = -expf(A_log[hh]) * sp;
    }
  }
}

// ---------------------------------------------------------------- 4-segment chunked recurrence (Round 9)
// 448 blocks: role = bI>>6 (0..3 real seg, 4..6 basis seg 1..3), blk = bI&63
// = (b, h, dvh). Segment = 512 steps = 16 chunks of C=32. Real: S0=0, write
// o[tbase..]; segs 0-2 export Sloc fp32. Basis: S0=I, V=0, write obasis
// fp16; segs 1-2 export Mst f16 (final state == transition matrix).
// LDS ~67 KB -> 2 blocks/CU (448 = 224 CU x 2, all co-resident).
#define SEGC 16
__global__ __launch_bounds__(256)
void recurrence_seg(const _Float16* __restrict__ gi,
                    const float* __restrict__ vprime,
                    const float* __restrict__ betab,
                    const float* __restrict__ glogb,
                    float* __restrict__ o,
                    float* __restrict__ Sloc,
                    _Float16* __restrict__ Mst,
                    _Float16* __restrict__ obasis)
{
  __shared__ _Float16 Q16[32][136];
  __shared__ _Float16 K16[32][136];
  __shared__ _Float16 KT16[128][40];   // single-buffered, psA-prescaled
  __shared__ _Float16 St16[64][136];   // fp16 shadow of state (dv-major)
  __shared__ _Float16 V16[32][64];     // block-swizzled (sw64)
  __shared__ _Float16 W16[32][64];     // block-swizzled, K*S0
  __shared__ float At32[32][36];       // A^T [j][i], pad 36 (write 2-way)
  __shared__ _Float16 B16[32][40];
  __shared__ _Float16 Ut16[64][40];    // U^T fp16 (dv-major)
  __shared__ float lgA[2][32], lgm1A[2][32], gm1E[2][32], bGA[2][32],
                   psA[2][32], betA[2][32], p31A[2];

  const int tid  = threadIdx.x;
  const int wid  = tid >> 6;
  const int lane = tid & 63;
  const int l16  = lane & 15;
  const int q8   = (lane >> 4) * 8;
  const int q4   = (lane >> 4) * 4;
  const int rg   = lane >> 4;            // solve: row group (8 rows)
  const int wc   = wid * 16 + l16;       // solve: dv column (0..63)

  const int role = blockIdx.x >> 6;      // 0..6
  const int blk  = blockIdx.x & 63;
  const int dvh  = blk & 1;
  const int h    = (blk >> 1) & 15;
  const int b    = blk >> 5;
  const bool basis = (role >= 4);
  const int seg  = basis ? (role - 3) : role;   // basis: 1..3, real: 0..3
  const int tbase = seg * 512;
  const int bh = b * 16 + h;

  const _Float16* gq = gi + (size_t)b * 2048 * 4096 + h * 128;
  const _Float16* gk = gq + 2048;
  const float* vsrc = vprime + (size_t)b * 2048 * 2048 + h * 128 + dvh * 64;
  float* ob = o + ((size_t)(b * 2048 + tbase) * 16 + h) * 128 + dvh * 64;
  _Float16* obb = obasis + (size_t)(seg - 1) * 2097152
                  + ((size_t)b * 512 * 16 + h) * 128 + dvh * 64;

  const int sr  = tid >> 3;              // staging row 0..31
  const int sc8 = tid & 7;
  const int c0  = sc8 * 16;              // q/k col base (16 f16 per thread)
  const int ktsw = (sc8 & 3) << 3;       // KT16 col swizzle key

  v4f sfr[8];                            // state frags [dv x dk] tiles
  #pragma unroll
  for (int tn = 0; tn < 8; tn++) {
    #pragma unroll
    for (int fr = 0; fr < 4; fr++)
      sfr[tn][fr] = (basis && (tn * 16 + l16) == (dvh * 64 + wid * 16 + q4 + fr))
                        ? 1.f : 0.f;
  }

  v8h pq0, pq1, pk0, pk1;
  v8h kon0, kon1;                        // normalized k of current chunk
  float4 pv0 = {0.f, 0.f, 0.f, 0.f}, pv1 = {0.f, 0.f, 0.f, 0.f};
  float pg = 0.f, pb = 0.f;

  auto stage_regs = [&](int t0) {
    pq0 = *(const v8h*)(gq + (size_t)(t0 + sr) * 4096 + c0);
    pq1 = *(const v8h*)(gq + (size_t)(t0 + sr) * 4096 + c0 + 8);
    pk0 = *(const v8h*)(gk + (size_t)(t0 + sr) * 4096 + c0);
    pk1 = *(const v8h*)(gk + (size_t)(t0 + sr) * 4096 + c0 + 8);
    if (!basis) {
      pv0 = *(const float4*)(vsrc + (size_t)(t0 + sr) * 2048 + sc8 * 8);
      pv1 = *(const float4*)(vsrc + (size_t)(t0 + sr) * 2048 + sc8 * 8 + 4);
    }
    if (tid < 32) {
      size_t bt_ = (size_t)(b * 2048 + t0 + tid) * 16 + h;
      pg = glogb[bt_];
      pb = betab[bt_];
    }
  };

  // normalize q/k -> Q16/K16 (+kon regs), V16 swizzled, decay scan scalars
  auto write_stage = [&](int pn) {
    float qf[16], kf[16];
    #pragma unroll
    for (int m = 0; m < 8; m++) {
      qf[m] = (float)pq0[m]; qf[m + 8] = (float)pq1[m];
      kf[m] = (float)pk0[m]; kf[m + 8] = (float)pk1[m];
    }
    float ssq = 0.f, ssk = 0.f;
    #pragma unroll
    for (int m = 0; m < 16; m++) { ssq += qf[m] * qf[m]; ssk += kf[m] * kf[m]; }
    ssq += __shfl_xor(ssq, 1); ssq += __shfl_xor(ssq, 2); ssq += __shfl_xor(ssq, 4);
    ssk += __shfl_xor(ssk, 1); ssk += __shfl_xor(ssk, 2); ssk += __shfl_xor(ssk, 4);
    float iq = 1.0f / fmaxf(sqrtf(ssq), 1e-12f);
    float ik = 1.0f / fmaxf(sqrtf(ssk), 1e-12f);
    v8h qo0, qo1, ko0, ko1;
    #pragma unroll
    for (int m = 0; m < 8; m++) {
      qo0[m] = (_Float16)(qf[m] * iq); qo1[m] = (_Float16)(qf[m + 8] * iq);
      ko0[m] = (_Float16)(kf[m] * ik); ko1[m] = (_Float16)(kf[m + 8] * ik);
    }
    *(v8h*)&Q16[sr][c0]     = qo0;
    *(v8h*)&Q16[sr][c0 + 8] = qo1;
    *(v8h*)&K16[sr][c0]     = ko0;
    *(v8h*)&K16[sr][c0 + 8] = ko1;
    kon0 = ko0; kon1 = ko1;
    {
      int swb = (sc8 ^ (sr & 7) ^ (sr >> 3)) & 7;
      v8h vo = {(_Float16)pv0.x, (_Float16)pv0.y, (_Float16)pv0.z, (_Float16)pv0.w,
                (_Float16)pv1.x, (_Float16)pv1.y, (_Float16)pv1.z, (_Float16)pv1.w};
      *(v8h*)&V16[sr][swb * 8] = vo;
    }
    if (tid < 32) {
      float s = pg;
      #pragma unroll
      for (int d = 1; d < 32; d <<= 1) {
        float t = __shfl_up(s, d, 64);
        if (lane >= d) s += t;
      }
      float lg31 = __shfl(s, 31, 64);
      float lgm1 = s - pg;               // log prod_{m<i} g_m
      lgA[pn][lane]   = s;
      lgm1A[pn][lane] = lgm1;
      float g1 = expf(lgm1);
      gm1E[pn][lane]  = g1;
      bGA[pn][lane]   = pb * g1;
      psA[pn][lane]   = expf(lg31 - s);  // P31/P_j <= 1
      betA[pn][lane]  = pb;
      if (lane == 0) p31A[pn] = expf(lg31);
    }
  };

  // ---- preloop: stage chunk 0, init state shadow (0 or I) ----
  stage_regs(tbase);
  for (int i = tid; i < 64 * 136; i += 256) {
    int r_ = i / 136, cc_ = i - r_ * 136;
    (&St16[0][0])[i] =
        (basis && cc_ == dvh * 64 + r_) ? (_Float16)1.f : (_Float16)0.f;
  }
  write_stage(0);
  __syncthreads();

  const v4f zf = {0.f, 0.f, 0.f, 0.f};

  for (int c = 0; c < SEGC; c++) {
    const int par = c & 1;

    // ===== top: issue next-chunk loads; KT for CURRENT chunk (kon, psA) ====
    if (c + 1 < SEGC) stage_regs(tbase + (c + 1) * 32);
    {
      float ps = psA[par][sr];
      #pragma unroll
      for (int m = 0; m < 8; m++) {
        KT16[c0 + m][sr ^ ktsw]     = (_Float16)((float)kon0[m] * ps);
        KT16[c0 + 8 + m][sr ^ ktsw] = (_Float16)((float)kon1[m] * ps);
      }
    }
    __builtin_amdgcn_sched_barrier(0);

    // ================= phase A: dense MFMAs + A/B assembly =================
    v4f kkf = zf, qkf = zf, w0f0 = zf, w0f1 = zf, o0f0 = zf, o0f1 = zf;
    {
      const int ai = (wid >> 1) * 16 + l16;  // KK/QK A rows (i)
      const int bj = (wid & 1) * 16 + l16;   // KK/QK B rows (j)
      #pragma unroll
      for (int ks = 0; ks < 4; ks++) {
        const int ko = ks * 32 + q8;
        v8h bs  = *(const v8h*)&St16[wid * 16 + l16][ko];  // S0 dv-slice
        v8h ak0 = *(const v8h*)&K16[l16][ko];
        v8h ak1 = *(const v8h*)&K16[16 + l16][ko];
        v8h aq0 = *(const v8h*)&Q16[l16][ko];
        v8h aq1 = *(const v8h*)&Q16[16 + l16][ko];
        w0f0 = __builtin_amdgcn_mfma_f32_16x16x32_f16(ak0, bs, w0f0, 0, 0, 0);
        w0f1 = __builtin_amdgcn_mfma_f32_16x16x32_f16(ak1, bs, w0f1, 0, 0, 0);
        o0f0 = __builtin_amdgcn_mfma_f32_16x16x32_f16(aq0, bs, o0f0, 0, 0, 0);
        o0f1 = __builtin_amdgcn_mfma_f32_16x16x32_f16(aq1, bs, o0f1, 0, 0, 0);
        v8h akk = *(const v8h*)&K16[ai][ko];
        v8h aqq = *(const v8h*)&Q16[ai][ko];
        v8h bkk = *(const v8h*)&K16[bj][ko];
        kkf = __builtin_amdgcn_mfma_f32_16x16x32_f16(akk, bkk, kkf, 0, 0, 0);
        qkf = __builtin_amdgcn_mfma_f32_16x16x32_f16(aqq, bkk, qkf, 0, 0, 0);
      }
    }
    {
      const int i0 = (wid >> 1) * 16, j = (wid & 1) * 16 + l16;
      #pragma unroll
      for (int fr = 0; fr < 4; fr++) {
        const int i = i0 + q4 + fr;
        float ex = expf(fminf(lgm1A[par][i] - lgA[par][j], 0.f));
        const bool lt = (j < i);
        At32[j][i] = lt ? betA[par][i] * ex * kkf[fr] : 0.f;
        B16[i][j]  = lt ? (_Float16)(ex * qkf[fr]) : (_Float16)0.f;
      }
      const int cc = wid * 16 + l16;
      #pragma unroll
      for (int fr = 0; fr < 4; fr++) {
        const int r1 = q4 + fr, r2 = 16 + q4 + fr;
        W16[r1][sw64(r1, cc)] = (_Float16)w0f0[fr];
        W16[r2][sw64(r2, cc)] = (_Float16)w0f1[fr];
      }
      // o0f0/o0f1 stay in registers: frag layout == phase-C write map
    }
    __syncthreads();

    // ================= phase B: triangular solve (I+A)U = R =================
    float ru[8];
    #pragma unroll
    for (int jj = 0; jj < 8; jj++) {
      const int row = rg * 8 + jj;
      const int sc_ = sw64(row, wc);
      float vv = (float)V16[row][sc_];
      float wv = (float)W16[row][sc_];
      ru[jj] = betA[par][row] * vv - bGA[par][row] * wv;
    }
    #pragma unroll
    for (int j = 0; j < 32; j++) {
      float uj = __shfl(ru[j & 7], (j >> 3) * 16 + l16, 64);
      const v4f a0 = *(const v4f*)&At32[j][rg * 8];
      const v4f a1 = *(const v4f*)&At32[j][rg * 8 + 4];
      ru[0] -= a0[0] * uj; ru[1] -= a0[1] * uj;
      ru[2] -= a0[2] * uj; ru[3] -= a0[3] * uj;
      ru[4] -= a1[0] * uj; ru[5] -= a1[1] * uj;
      ru[6] -= a1[2] * uj; ru[7] -= a1[3] * uj;
    }
    {
      v8h uo;
      #pragma unroll
      for (int jj = 0; jj < 8; jj++) uo[jj] = (_Float16)ru[jj];
      *(v8h*)&Ut16[wc][rg * 8] = uo;
    }
    __syncthreads();

    // ========== phase C: O = Gm1*o0f + B U ; S = P31*S + KTs^T U ===========
    {
      v8h bu = *(const v8h*)&Ut16[wid * 16 + l16][q8];
      #pragma unroll
      for (int t2i = 0; t2i < 2; t2i++) {
        v8h a = *(const v8h*)&B16[t2i * 16 + l16][q8];
        v4f d = __builtin_amdgcn_mfma_f32_16x16x32_f16(a, bu, zf, 0, 0, 0);
        #pragma unroll
        for (int fr = 0; fr < 4; fr++) {
          const int i = t2i * 16 + q4 + fr;
          const int cc = wid * 16 + l16;
          float o0 = (t2i == 0) ? o0f0[fr] : o0f1[fr];
          float val = gm1E[par][i] * o0 + d[fr];
          size_t off = (size_t)(c * 32 + i) * 2048 + cc;
          if (basis) obb[off] = (_Float16)val;
          else       ob[off] = val;
        }
      }
      const float p31 = p31A[par];
      #pragma unroll
      for (int tn = 0; tn < 8; tn++) {
        v8h bk = *(const v8h*)&KT16[tn * 16 + l16][q8 ^ ((tn & 3) << 3)];
        v4f sc = {sfr[tn][0] * p31, sfr[tn][1] * p31,
                  sfr[tn][2] * p31, sfr[tn][3] * p31};
        sfr[tn] = __builtin_amdgcn_mfma_f32_16x16x32_f16(bu, bk, sc, 0, 0, 0);
        #pragma unroll
        for (int fr = 0; fr < 4; fr++)
          St16[wid * 16 + q4 + fr][tn * 16 + l16] = (_Float16)sfr[tn][fr];
      }
    }
    if (c + 1 < SEGC) write_stage((c + 1) & 1);
    __syncthreads();
  }

  // exports: Sloc (real segs 0-2, fp32), Mst (basis segs 1-2, f16)
  if (!basis && seg < 3) {
    float* sg = Sloc + ((size_t)seg * 32 + bh) * 16384;
    #pragma unroll
    for (int tn = 0; tn < 8; tn++)
      #pragma unroll
      for (int fr = 0; fr < 4; fr++)
        sg[(size_t)(dvh * 64 + wid * 16 + q4 + fr) * 128 + tn * 16 + l16] =
            sfr[tn][fr];
  }
  if (basis && seg <= 2) {
    _Float16* mg = Mst + ((size_t)(seg - 1) * 32 + bh) * 16384;
    #pragma unroll
    for (int tn = 0; tn < 8; tn++)
      #pragma unroll
      for (int fr = 0; fr < 4; fr++)
        mg[(size_t)(dvh * 64 + wid * 16 + q4 + fr) * 128 + tn * 16 + l16] =
            (_Float16)sfr[tn][fr];
  }
}

// ---------------------------------------------------------------- state compose
// Stored-transpose layout: SinS_{i+1} = SinS_i @ Mst_i + Sloc_i (plain
// matmul over k''). 32 blocks = (b,h); two sequential 128^3 MFMA steps.
__global__ __launch_bounds__(256)
void compose_state(const float* __restrict__ Sloc, const _Float16* __restrict__ Mst,
                   _Float16* __restrict__ SinS)
{
  __shared__ _Float16 AL[128][136];
  __shared__ _Float16 BL[128][136];
  const int bh = blockIdx.x;
  const int tid = threadIdx.x;
  const int wid = tid >> 6, lane = tid & 63;
  const int l16 = lane & 15, q8 = (lane >> 4) * 8, q4 = (lane >> 4) * 4;

  // SinS[0] = cast(Sloc[0]); keep in AL
  {
    const float* s0 = Sloc + (size_t)bh * 16384;
    _Float16* d0 = SinS + (size_t)bh * 16384;
    for (int i = tid; i < 2048; i += 256) {
      int r = i >> 4, c8 = (i & 15) * 8;
      v8h t;
      #pragma unroll
      for (int m = 0; m < 8; m++) t[m] = (_Float16)s0[(size_t)r * 128 + c8 + m];
      *(v8h*)&AL[r][c8] = t;
      *(v8h*)(d0 + (size_t)r * 128 + c8) = t;
    }
  }
  __syncthreads();

  for (int st = 0; st < 2; st++) {
    // BL = Mst[st]^T
    const _Float16* ms = Mst + ((size_t)st * 32 + bh) * 16384;
    for (int i = tid; i < 2048; i += 256) {
      int r = i >> 4, c8 = (i & 15) * 8;
      v8h t = *(const v8h*)(ms + (size_t)r * 128 + c8);
      #pragma unroll
      for (int m = 0; m < 8; m++) BL[c8 + m][r] = t[m];
    }
    __syncthreads();

    v4f acc[2][8];
    #pragma unroll
    for (int rt = 0; rt < 2; rt++)
      #pragma unroll
      for (int ct = 0; ct < 8; ct++) acc[rt][ct] = v4f{0.f, 0.f, 0.f, 0.f};
    #pragma unroll
    for (int ks = 0; ks < 4; ks++) {
      v8h a0 = *(const v8h*)&AL[wid * 32 + l16][ks * 32 + q8];
      v8h a1 = *(const v8h*)&AL[wid * 32 + 16 + l16][ks * 32 + q8];
      #pragma unroll
      for (int ct = 0; ct < 8; ct++) {
        v8h bfv = *(const v8h*)&BL[ct * 16 + l16][ks * 32 + q8];
        acc[0][ct] = __builtin_amdgcn_mfma_f32_16x16x32_f16(a0, bfv, acc[0][ct], 0, 0, 0);
        acc[1][ct] = __builtin_amdgcn_mfma_f32_16x16x32_f16(a1, bfv, acc[1][ct], 0, 0, 0);
      }
    }
    __syncthreads();   // all AL reads done before rewrite

    const float* sn = Sloc + ((size_t)(st + 1) * 32 + bh) * 16384;
    _Float16* dn = SinS + ((size_t)(st + 1) * 32 + bh) * 16384;
    #pragma unroll
    for (int rt = 0; rt < 2; rt++) {
      #pragma unroll
      for (int ct = 0; ct < 8; ct++) {
        #pragma unroll
        for (int fr = 0; fr < 4; fr++) {
          const int row = wid * 32 + rt * 16 + q4 + fr;
          const int col = ct * 16 + l16;
          float val = acc[rt][ct][fr] + sn[(size_t)row * 128 + col];
          _Float16 hv = (_Float16)val;
          AL[row][col] = hv;
          dn[(size_t)row * 128 + col] = hv;
        }
      }
    }
    __syncthreads();
  }
}

// ---------------------------------------------------------------- apply basis correction
// o[b, (ss+1)*512 + t, h, :] += o_basis[ss][b, t, h, :dk] @ SinS[ss][dv][dk]^T
// 384 blocks = 3 segs x 4 t-tiles x 32 (b,h).
__global__ __launch_bounds__(256)
void apply_basis(const _Float16* __restrict__ obasis,
                 const _Float16* __restrict__ SinS,
                 float* __restrict__ o)
{
  __shared__ _Float16 Ao[128][136];
  __shared__ _Float16 Bs[128][136];
  const int ss = blockIdx.x >> 7;        // 0..2
  const int rem = blockIdx.x & 127;
  const int tt = rem >> 5;               // 0..3
  const int bh = rem & 31;
  const int b = bh >> 4, h = bh & 15;
  const int tid = threadIdx.x;
  const int wid = tid >> 6, lane = tid & 63;
  const int l16 = lane & 15, q8 = (lane >> 4) * 8, q4 = (lane >> 4) * 4;

  const _Float16* asrc = obasis + (size_t)ss * 2097152
                         + ((size_t)(b * 512 + tt * 128) * 16 + h) * 128;
  for (int i = tid; i < 2048; i += 256) {
    int r = i >> 4, c8 = (i & 15) * 8;
    *(v8h*)&Ao[r][c8] = *(const v8h*)(asrc + (size_t)r * 2048 + c8);
  }
  const _Float16* ssrc = SinS + ((size_t)ss * 32 + bh) * 16384;
  for (int i = tid; i < 2048; i += 256) {
    int r = i >> 4, c8 = (i & 15) * 8;
    *(v8h*)&Bs[r][c8] = *(const v8h*)(ssrc + (size_t)r * 128 + c8);
  }
  __syncthreads();

  v4f acc[2][8];
  #pragma unroll
  for (int rt = 0; rt < 2; rt++)
    #pragma unroll
    for (int ct = 0; ct < 8; ct++) acc[rt][ct] = v4f{0.f, 0.f, 0.f, 0.f};
  #pragma unroll
  for (int ks = 0; ks < 4; ks++) {
    v8h af0 = *(const v8h*)&Ao[wid * 32 + l16][ks * 32 + q8];
    v8h af1 = *(const v8h*)&Ao[wid * 32 + 16 + l16][ks * 32 + q8];
    #pragma unroll
    for (int ct = 0; ct < 8; ct++) {
      v8h bf = *(const v8h*)&Bs[ct * 16 + l16][ks * 32 + q8];
      acc[0][ct] = __builtin_amdgcn_mfma_f32_16x16x32_f16(af0, bf, acc[0][ct], 0, 0, 0);
      acc[1][ct] = __builtin_amdgcn_mfma_f32_16x16x32_f16(af1, bf, acc[1][ct], 0, 0, 0);
    }
  }
  float* obp = o + ((size_t)(b * 2048 + (ss + 1) * 512 + tt * 128) * 16 + h) * 128;
  #pragma unroll
  for (int rt = 0; rt < 2; rt++) {
    #pragma unroll
    for (int ct = 0; ct < 8; ct++) {
      #pragma unroll
      for (int fr = 0; fr < 4; fr++) {
        const int row = wid * 32 + rt * 16 + q4 + fr;
        const int col = ct * 16 + l16;
        obp[(size_t)row * 2048 + col] += acc[rt][ct][fr];
      }
    }
  }
}

// ---------------------------------------------------------------- rmsnorm * silu(gate)
__global__ __launch_bounds__(256)
void rms_gate(const float* __restrict__ o, const _Float16* __restrict__ vg,
              const float* __restrict__ normw, _Float16* __restrict__ yh)
{
  int task = blockIdx.x * 4 + (threadIdx.x >> 6);  // bt*16+h, 0..65535
  int lane = threadIdx.x & 63;
  int bt = task >> 4, h = task & 15;
  float2 v = *(const float2*)(o + (size_t)task * 128 + lane * 2);
  float ss = v.x * v.x + v.y * v.y;
  #pragma unroll
  for (int m = 1; m < 64; m <<= 1) ss += __shfl_xor(ss, m);
  float r = rsqrtf(ss * (1.0f / 128.0f) + 1e-6f);
  v2h gt2 = *(const v2h*)(vg + (size_t)bt * 4096 + 2048 + h * 128 + lane * 2);
  float gx = (float)gt2[0], gy = (float)gt2[1];
  float2 nw = *(const float2*)(normw + lane * 2);
  float g0 = gx / (1.0f + expf(-gx));
  float g1 = gy / (1.0f + expf(-gy));
  v2h outp = {(_Float16)(v.x * r * nw.x * g0), (_Float16)(v.y * r * nw.y * g1)};
  *(v2h*)(yh + (size_t)bt * 2048 + h * 128 + lane * 2) = outp;
}

// ---------------------------------------------------------------- launch
extern "C" void kernel_launch(void* const* d_in, const int* in_sizes, int n_in,
                              void* d_out, int out_size, void* d_ws, size_t ws_size,
                              hipStream_t stream)
{
  (void)in_sizes; (void)n_in; (void)out_size;
  const float* x       = (const float*)d_in[0];
  const float* Wq      = (const float*)d_in[1];
  const float* Wk      = (const float*)d_in[2];
  const float* Wv      = (const float*)d_in[3];
  const float* Wb      = (const float*)d_in[4];
  const float* Wa      = (const float*)d_in[5];
  const float* dt_bias = (const float*)d_in[6];
  const float* A_log   = (const float*)d_in[7];
  const float* gen_w1  = (const float*)d_in[8];
  const float* gen_w2  = (const float*)d_in[9];
  const float* gen_b2  = (const float*)d_in[10];
  const float* normw   = (const float*)d_in[11];
  const float* Wg      = (const float*)d_in[12];
  const float* Wo      = (const float*)d_in[13];

  // ---- workspace pool (explicit aliasing; peak ~185 MB, known to fit) ----
  const size_t SZ_GI   = 4096ull * 4096 * 2;   // 33.5 MB  f16 q|k (pre-norm)
  const size_t SZ_VG   = 4096ull * 4096 * 2;   // 33.5 MB  f16 v|gate
  const size_t SZ_WT   = 8192ull * 2048 * 2;   // 33.5 MB  f16 transposed weights (reused)
  const size_t SZ_D    = 4096ull * 2048 * 2;   // 16.8 MB  xh -> hid -> yh
  const size_t SZ_KC   = 2048ull * 8192 * 2;   // 33.5 MB  kern chunk (reused)
  const size_t SZ_VP   = 4096ull * 2048 * 4;   // 33.5 MB  fp32 v'
  const size_t SZ_SM   = 4096ull * 16 * 4;     //  0.26 MB x2
  const size_t NEEDED = SZ_GI + SZ_VG + SZ_WT + SZ_D + SZ_KC + SZ_VP + 2 * SZ_SM;
  if (ws_size < NEEDED) return;

  char* w = (char*)d_ws;
  _Float16* gi     = (_Float16*)(w);
  _Float16* vg     = (_Float16*)(w + SZ_GI);
  _Float16* Wt     = (_Float16*)(w + SZ_GI + SZ_VG);
  char*     Dreg   =            (w + SZ_GI + SZ_VG + SZ_WT);
  _Float16* kernc  = (_Float16*)(w + SZ_GI + SZ_VG + SZ_WT + SZ_D);
  float*    vprime = (float*)   (w + SZ_GI + SZ_VG + SZ_WT + SZ_D + SZ_KC);
  float*    betab  = (float*)   (w + SZ_GI + SZ_VG + SZ_WT + SZ_D + SZ_KC + SZ_VP);
  float*    glogb  = (float*)   (w + SZ_GI + SZ_VG + SZ_WT + SZ_D + SZ_KC + SZ_VP + SZ_SM);
  _Float16* xh  = (_Float16*)Dreg;  // until G1b
  _Float16* hid = (_Float16*)Dreg;  // G2 -> G3
  _Float16* yh  = (_Float16*)Dreg;  // rms_gate -> G4
  float* obuf = (float*)d_out;      // o lives in d_out until G4 overwrites

  // recurrence scratch aliases Wt (dead between G3 gemms and G4 transpose):
  // obasis 3x4.19MB f16, Sloc 3x2.1MB f32, Mst 2x1.05MB f16, SinS 3x1.05MB f16
  _Float16* obasis = (_Float16*)(w + SZ_GI + SZ_VG);
  float*    Sloc   = (float*)   (w + SZ_GI + SZ_VG + 12582912ull);
  _Float16* MstB   = (_Float16*)(w + SZ_GI + SZ_VG + 12582912ull + 6291456ull);
  _Float16* SinS   = (_Float16*)(w + SZ_GI + SZ_VG + 12582912ull + 6291456ull + 2097152ull);

  dim3 blk(256);
  dim3 blk512(512);

  cast_f32_f16<<<8192, blk, 0, stream>>>(x, xh, 4096 * 2048 / 4);

  // G1a: q|k  (M=4096, N=4096, K=2048 -> 256 wgs)
  transpose_cast<<<dim3(64, 64), blk, 0, stream>>>(Wq, Wt, 2048, 2048);
  transpose_cast<<<dim3(64, 64), blk, 0, stream>>>(Wk, Wt + 2048 * 2048, 2048, 2048);
  gemm256<3><<<256, blk512, 0, stream>>>(xh, Wt, gi, nullptr, 4096, 4096, 2048);

  // G1b: v|gate
  transpose_cast<<<dim3(64, 64), blk, 0, stream>>>(Wv, Wt, 2048, 2048);
  transpose_cast<<<dim3(64, 64), blk, 0, stream>>>(Wg, Wt + 2048 * 2048, 2048, 2048);
  gemm256<3><<<256, blk512, 0, stream>>>(xh, Wt, vg, nullptr, 4096, 4096, 2048);

  // G2: hid = silu(gi @ gen_w1)  (M=4096, N=2048, K=4096 -> 128 wgs)
  transpose_cast<<<dim3(64, 128), blk, 0, stream>>>(gen_w1, Wt, 4096, 2048);
  gemm256<1><<<128, blk512, 0, stream>>>(gi, Wt, hid, nullptr, 4096, 2048, 4096);

  // G3 + conv, chunked per batch  (M=2048, N=8192, K=2048 -> 256 wgs)
  transpose_cast<<<dim3(256, 64), blk, 0, stream>>>(gen_w2, Wt, 2048, 8192);
  for (int chunk = 0; chunk < 2; chunk++) {
    gemm256<2><<<256, blk512, 0, stream>>>(hid + (size_t)chunk * 2048 * 2048, Wt,
                                           kernc, gen_b2, 2048, 8192, 2048);
    conv_silu<<<16384, blk, 0, stream>>>(vg, kernc, vprime, chunk);
  }

  beta_decay<<<4096, blk, 0, stream>>>(x, Wb, Wa, dt_bias, A_log, betab, glogb);
  recurrence_seg<<<448, blk, 0, stream>>>(gi, vprime, betab, glogb, obuf,
                                          Sloc, MstB, obasis);
  compose_state<<<32, blk, 0, stream>>>(Sloc, MstB, SinS);
  apply_basis<<<384, blk, 0, stream>>>(obasis, SinS, obuf);
  rms_gate<<<16384, blk, 0, stream>>>(obuf, vg, normw, yh);

  // G4: out = y @ Wo  (M=4096, N=2048, K=2048 -> 128 wgs)
  transpose_cast<<<dim3(64, 64), blk, 0, stream>>>(Wo, Wt, 2048, 2048);
  gemm256<0><<<128, blk512, 0, stream>>>(yh, Wt, (float*)d_out, nullptr, 4096, 2048, 2048);
}